// Round 20
// baseline (71.813 us; speedup 1.0000x reference)
//
#include <hip/hip_runtime.h>
#include <hip/hip_bf16.h>

constexpr int kT = 32768;   // tokens = B*N
constexpr int kD = 128;
constexpr int kH = 256;
constexpr int kE = 16;

typedef __bf16 bf16x8 __attribute__((ext_vector_type(8)));
typedef unsigned short u16x8 __attribute__((ext_vector_type(8)));
typedef unsigned short u16x4 __attribute__((ext_vector_type(4)));
typedef float f32x4 __attribute__((ext_vector_type(4)));

#define LDX 136   // xs row stride (ushort) = 128 + 8 pad
#define LDQ 72    // hs quarter row stride (ushort) = 64 + 8 pad

constexpr int NB_TP   = 272;     // transpose tiles (17 W1-like + 17 W2-like, 8 each)
constexpr int NB_GATE = kT / 64; // 512
constexpr int CNT_STRIDE = 32;   // counters padded to 128 B (own cache line)
constexpr int EXP_GRID = 1040;   // max expert tiles: 16 + 65536/64

__device__ __forceinline__ unsigned short f2bf(float f) {
  unsigned int u = __float_as_uint(f);
  u += 0x7FFFu + ((u >> 16) & 1u);   // round-to-nearest-even
  return (unsigned short)(u >> 16);
}
__device__ __forceinline__ float bf2f(unsigned short s) {
  return __uint_as_float((unsigned int)s << 16);
}
// barrier WITHOUT the vmcnt(0) drain __syncthreads carries: LDS ops are
// ordered (lgkmcnt 0), register-destined global loads stay in flight.
__device__ __forceinline__ void bar_lgkm() {
  asm volatile("s_waitcnt lgkmcnt(0)" ::: "memory");
  __builtin_amdgcn_s_barrier();
  asm volatile("" ::: "memory");
}

// ---------- fused front-end: weight transpose | gating + x slot-scatter -----
__global__ __launch_bounds__(256) void front_kernel(
    const float* __restrict__ x, const float* __restrict__ Wg,
    const float* __restrict__ bg,
    const float* __restrict__ W1, const float* __restrict__ W2,
    const float* __restrict__ Wu1, const float* __restrict__ Wu2,
    unsigned short* __restrict__ xb, unsigned short* __restrict__ W1t,
    unsigned short* __restrict__ W2t, unsigned short* __restrict__ Wu1t,
    unsigned short* __restrict__ Wu2t,
    int* __restrict__ cnt, float* __restrict__ bgate,
    int* __restrict__ tpos, float* __restrict__ omega,
    unsigned short* __restrict__ xg)
{
  __shared__ __align__(16) char smem[46848];
  const int tid = threadIdx.x;
  const int b = blockIdx.x;

  if (b < NB_TP) {
    // ---- LDS-tiled transpose fp32 [R][C] -> bf16 [C][R], 64x64 tiles
    int bb = b;
    const float* src; unsigned short* dst; int R, C, r0, c0;
    if (bb < 136) {                 // W1-like: [128][256] -> [256][128]
      int m = bb >> 3, t8 = bb & 7;
      R = 128; C = 256;
      src = (m < 16) ? W1 + (size_t)m * 32768 : Wu1;
      dst = (m < 16) ? W1t + (size_t)m * 32768 : Wu1t;
      r0 = (t8 & 1) * 64; c0 = (t8 >> 1) * 64;
    } else {                        // W2-like: [256][128] -> [128][256]
      bb -= 136;
      int m = bb >> 3, t8 = bb & 7;
      R = 256; C = 128;
      src = (m < 16) ? W2 + (size_t)m * 32768 : Wu2;
      dst = (m < 16) ? W2t + (size_t)m * 32768 : Wu2t;
      r0 = (t8 >> 1) * 64; c0 = (t8 & 1) * 64;
    }
    unsigned short (*tl)[72] = reinterpret_cast<unsigned short(*)[72]>(smem);
#pragma unroll
    for (int i = 0; i < 4; ++i) {
      int s = i * 256 + tid;
      int r = s >> 4, c4 = s & 15;
      float4 v = *reinterpret_cast<const float4*>(&src[(size_t)(r0 + r) * C + c0 + c4 * 4]);
      tl[c4 * 4 + 0][r] = f2bf(v.x);
      tl[c4 * 4 + 1][r] = f2bf(v.y);
      tl[c4 * 4 + 2][r] = f2bf(v.z);
      tl[c4 * 4 + 3][r] = f2bf(v.w);
    }
    __syncthreads();
#pragma unroll
    for (int i = 0; i < 2; ++i) {
      int s = i * 256 + tid;
      int c = s >> 3, seg = s & 7;
      uint4 v = *reinterpret_cast<const uint4*>(&tl[c][seg * 8]);
      *reinterpret_cast<uint4*>(&dst[(size_t)(c0 + c) * R + r0 + seg * 8]) = v;
    }
    return;
  }

  // ---- gating: logits (fp64 accum), top-2, scatter x rows to slots --------
  {
    float* sWt = reinterpret_cast<float*>(smem);            // [16][132]
    float* sX  = reinterpret_cast<float*>(smem + 8448);     // [64][132]
    float* sL  = reinterpret_cast<float*>(smem + 42240);    // [64][17]
    int* sSlot = reinterpret_cast<int*>(smem + 42240);      // [128] (reuses sL)
    int* hcnt  = reinterpret_cast<int*>(smem + 46592);      // [16]
    int* hbase = reinterpret_cast<int*>(smem + 46656);      // [16]
    const int t0 = (b - NB_TP) * 64;

    if (tid < kE) hcnt[tid] = 0;
    for (int i = tid; i < kD * kE; i += 256) {              // Wg[d][e] -> sWt[e][d]
      int d = i >> 4, e = i & 15;
      sWt[e * 132 + d] = Wg[i];
    }
    const float4* xv = reinterpret_cast<const float4*>(x + (size_t)t0 * kD);
    for (int i = tid; i < 64 * kD / 4; i += 256) {
      int r = i >> 5, c4 = i & 31;
      *reinterpret_cast<float4*>(&sX[r * 132 + c4 * 4]) = xv[i];
    }
    __syncthreads();

    const int e = tid & 15, tq = tid >> 4;
    const double bgd = (double)bg[e];
    const float4* wr = reinterpret_cast<const float4*>(&sWt[e * 132]);
    double acc[4] = {0.0, 0.0, 0.0, 0.0};    // one chain per token (4-way ILP)
#pragma unroll
    for (int d4 = 0; d4 < 32; ++d4) {
      float4 wa = wr[d4];                    // load weight row once, reuse x4
#pragma unroll
      for (int p = 0; p < 4; ++p) {
        float4 xa = *reinterpret_cast<const float4*>(&sX[(p * 16 + tq) * 132 + d4 * 4]);
        acc[p] += (double)xa.x * (double)wa.x + (double)xa.y * (double)wa.y
                + (double)xa.z * (double)wa.z + (double)xa.w * (double)wa.w;
      }
    }
#pragma unroll
    for (int p = 0; p < 4; ++p)
      sL[(p * 16 + tq) * 17 + e] = (float)(acc[p] + bgd);
    // fold x fp32->bf16 cast here (sX already staged)
#pragma unroll
    for (int p = 0; p < 4; ++p) {
      int idx = p * 256 + tid;
      int r = idx >> 4, c8 = (idx & 15) * 8;
      const float* sp = &sX[r * 132 + c8];
      u16x8 v;
#pragma unroll
      for (int j = 0; j < 8; ++j) v[j] = f2bf(sp[j]);
      *reinterpret_cast<u16x8*>(&xb[(size_t)(t0 + r) * kD + c8]) = v;
    }
    __syncthreads();

    int e0 = 0, e1 = 0, lp0 = 0, lp1 = 0;
    float g0 = 0.f, g1 = 0.f;
    const int t = t0 + tid;
    if (tid < 64) {
      float v0 = -3.4e38f, v1 = -3.4e38f;
      for (int i = 0; i < kE; ++i) {
        float v = sL[tid * 17 + i];
        if (v > v0) { v1 = v0; e1 = e0; v0 = v; e0 = i; }
        else if (v > v1) { v1 = v; e1 = i; }
      }
      float r = expf(v1 - v0);
      g0 = 1.f / (1.f + r);
      g1 = 1.f - g0;
      omega[t] = 1.f - g0;                   // dense omega (uni pass is linear)
      lp0 = atomicAdd(&hcnt[e0], 1);
      lp1 = atomicAdd(&hcnt[e1], 1);
    }
    __syncthreads();
    if (tid < kE)
      hbase[tid] = atomicAdd(&cnt[tid * CNT_STRIDE], hcnt[tid]);
    __syncthreads();                         // last sL read was before; sSlot may alias
    if (tid < 64) {
      int p0 = hbase[e0] + lp0;
      bgate[e0 * kT + p0] = g0;
      int p1 = hbase[e1] + lp1;
      bgate[e1 * kT + p1] = g1;
      tpos[2 * t]     = (e0 << 16) | p0;      // token -> expert slots (for fold)
      tpos[2 * t + 1] = (e1 << 16) | p1;
      sSlot[2 * tid]     = e0 * kT + p0;      // slots for x scatter below
      sSlot[2 * tid + 1] = e1 * kT + p1;
    }
    __syncthreads();
    // ---- scatter x rows to slot-ordered xg (stores: latency-tolerant) ----
    for (int i = tid; i < 128 * 16; i += 256) {   // 128 slot-rows x 16 chunks
      int sl = i >> 4, seg = i & 15;
      int r = sl >> 1;                            // token row in this tile
      int slot = sSlot[sl];
      const float* sp = &sX[r * 132 + seg * 8];
      u16x8 v;
#pragma unroll
      for (int j = 0; j < 8; ++j) v[j] = f2bf(sp[j]);
      *reinterpret_cast<u16x8*>(xg + (size_t)slot * kD + seg * 8) = v;
    }
  }
}

// ---------- expert tiles: R17 pipeline, LINEAR xg stage (no indirection) ----
#define LOAD_W1(BUF, HQ)                                                      \
  _Pragma("unroll")                                                           \
  for (int kk = 0; kk < 4; ++kk)                                              \
    W1r[BUF][kk] = *reinterpret_cast<const bf16x8*>(                          \
        Bw1 + (size_t)((HQ) * 64 + w * 16 + lr) * kD + kk * 32 + lg * 8);

#define LOAD_W2(BUF, HQ)                                                      \
  _Pragma("unroll")                                                           \
  for (int n = 0; n < 2; ++n)                                                 \
    _Pragma("unroll")                                                         \
    for (int k2 = 0; k2 < 2; ++k2)                                            \
      W2r[BUF][n * 2 + k2] = *reinterpret_cast<const bf16x8*>(                \
          Bw2 + (size_t)(w * 32 + n * 16 + lr) * kH + (HQ) * 64 + k2 * 32 + lg * 8);

__global__ __launch_bounds__(256) void moe_expert_kernel(
    const unsigned short* __restrict__ xg,
    const unsigned short* __restrict__ W1t,
    const unsigned short* __restrict__ W2t,
    const float* __restrict__ b1, const float* __restrict__ b2,
    const int* __restrict__ cnt, const float* __restrict__ bgate,
    unsigned short* __restrict__ eo)
{
  __shared__ alignas(16) char smem[27136];
  unsigned short* xs = reinterpret_cast<unsigned short*>(smem);           // [64][136]
  unsigned short* hs = reinterpret_cast<unsigned short*>(smem + 17408);   // [64][72]
  float* gts  = reinterpret_cast<float*>(smem + 26880);                   // [64]
  unsigned short* stB = reinterpret_cast<unsigned short*>(smem);          // bf16 stage (aliases xs)
  const int tid = threadIdx.x;
  const int bid = blockIdx.x;

  // ---- block -> (e, tile) map; eobase = sum counts of experts < e
  int c16[16];
#pragma unroll
  for (int i = 0; i < 16; ++i) c16[i] = cnt[i * CNT_STRIDE];
  int e = -1, tile = 0, eobase = 0, accb = 0;
#pragma unroll
  for (int i = 0; i < 16; ++i) {
    int tl = (c16[i] + 63) >> 6;
    if (e < 0) {
      if (bid < accb + tl) { e = i; tile = bid - accb; }
      else { accb += tl; eobase += c16[i]; }
    }
  }
  if (e < 0) return;
  const int rows = min(64, c16[e] - tile * 64);

  const int w = tid >> 6, l = tid & 63, lr = l & 15, lg = l >> 4;
  const int gr = tid >> 4, gc = (tid & 15) * 8;
  const f32x4 z4 = {0.f, 0.f, 0.f, 0.f};

  const unsigned short* Bw1 = W1t + (size_t)e * kH * kD;
  const unsigned short* Bw2 = W2t + (size_t)e * kD * kH;
  const float* bs1 = b1 + (size_t)e * kH;
  const float* bs2 = b2 + (size_t)e * kD;

  // ---- issue quarter-0 weights FIRST: they fly during the stage + barrier
  bf16x8 W1r[2][4], W2r[2][4];
  LOAD_W1(0, 0); LOAD_W2(0, 0);
  float b1q[4];
#pragma unroll
  for (int hq = 0; hq < 4; ++hq) b1q[hq] = bs1[hq * 64 + w * 16 + lr];
  float b2v[2];
#pragma unroll
  for (int n = 0; n < 2; ++n) b2v[n] = bs2[w * 32 + n * 16 + lr];

  // ---- LINEAR stage from xg (front pre-scattered) + per-slot gates --------
  {
    float gtR[4];
#pragma unroll
    for (int p = 0; p < 4; ++p) {
      int r = p * 16 + gr;
      gtR[p] = (r < rows) ? bgate[e * kT + tile * 64 + r] : 0.f;
    }
#pragma unroll
    for (int p = 0; p < 4; ++p) {
      uint4 v = *reinterpret_cast<const uint4*>(
          xg + (size_t)(e * kT + tile * 64 + p * 16 + gr) * kD + gc);
      *reinterpret_cast<uint4*>(&xs[(p * 16 + gr) * LDX + gc]) = v;
    }
    if ((tid & 15) == 0) {
#pragma unroll
      for (int p = 0; p < 4; ++p) gts[p * 16 + gr] = gtR[p];
    }
  }
  f32x4 acc2[4][2];
#pragma unroll
  for (int m = 0; m < 4; ++m)
#pragma unroll
    for (int n = 0; n < 2; ++n) acc2[m][n] = z4;
  bar_lgkm();                                        // xs ready (weights in flight)

  // ---- four h-quarters, weights for hq+1 prefetched across barriers
#pragma unroll
  for (int hq = 0; hq < 4; ++hq) {
    const int cur = hq & 1;
    if (hq < 3) {
      const int nxt = cur ^ 1;
      LOAD_W1(nxt, hq + 1);                          // in flight over 2 barriers
      LOAD_W2(nxt, hq + 1);
    }
    f32x4 acc[4];
#pragma unroll
    for (int m = 0; m < 4; ++m) acc[m] = z4;
#pragma unroll
    for (int kk = 0; kk < 4; ++kk) {
      bf16x8 a[4];
#pragma unroll
      for (int m = 0; m < 4; ++m)
        a[m] = *reinterpret_cast<const bf16x8*>(xs + (m * 16 + lr) * LDX + kk * 32 + lg * 8);
#pragma unroll
      for (int m = 0; m < 4; ++m)
        acc[m] = __builtin_amdgcn_mfma_f32_16x16x32_bf16(a[m], W1r[cur][kk], acc[m], 0, 0, 0);
    }
#pragma unroll
    for (int m = 0; m < 4; ++m)
#pragma unroll
      for (int q = 0; q < 4; ++q) {
        float v = acc[m][q] + b1q[hq];
        v = fmaxf(v, 0.f);
        hs[(m * 16 + lg * 4 + q) * LDQ + w * 16 + lr] = f2bf(v);
      }
    bar_lgkm();                                      // hs quarter ready
#pragma unroll
    for (int k2 = 0; k2 < 2; ++k2) {
      bf16x8 a[4];
#pragma unroll
      for (int m = 0; m < 4; ++m)
        a[m] = *reinterpret_cast<const bf16x8*>(hs + (m * 16 + lr) * LDQ + k2 * 32 + lg * 8);
#pragma unroll
      for (int m = 0; m < 4; ++m)
#pragma unroll
        for (int n = 0; n < 2; ++n)
          acc2[m][n] = __builtin_amdgcn_mfma_f32_16x16x32_bf16(a[m], W2r[cur][n * 2 + k2], acc2[m][n], 0, 0, 0);
    }
    bar_lgkm();                                      // hs consumed (next quarter)
  }

  // ---- epilogue: stage g*(acc2+b2) bf16, full-line vector stores to eo
#pragma unroll
  for (int m = 0; m < 4; ++m)
#pragma unroll
    for (int q = 0; q < 4; ++q) {
      int r = m * 16 + lg * 4 + q;
      float g = gts[r];
#pragma unroll
      for (int n = 0; n < 2; ++n)
        stB[r * LDX + w * 32 + n * 16 + lr] = f2bf(g * (acc2[m][n][q] + b2v[n]));
    }
  bar_lgkm();
  unsigned short* dst = eo + (size_t)(eobase + tile * 64) * kD;
#pragma unroll
  for (int j = 0; j < 4; ++j) {
    int gidx = j * 256 + tid;
    int r = gidx >> 4, seg = gidx & 15;
    if (r < rows) {
      uint4 v = *reinterpret_cast<const uint4*>(&stB[r * LDX + seg * 8]);
      *reinterpret_cast<uint4*>(dst + (size_t)r * kD + seg * 8) = v;
    }
  }
}

// ---------- uni + combine: linear tiles, out = omega*uni + eo0 + eo1 --------
__global__ __launch_bounds__(256) void uni_combine_kernel(
    const unsigned short* __restrict__ xb,
    const unsigned short* __restrict__ Wu1t,
    const unsigned short* __restrict__ Wu2t,
    const float* __restrict__ bu1, const float* __restrict__ bu2,
    const float* __restrict__ omega, const int* __restrict__ cnt,
    const int* __restrict__ tpos, const unsigned short* __restrict__ eo,
    float* __restrict__ out)
{
  __shared__ alignas(16) char smem[27456];
  unsigned short* xs = reinterpret_cast<unsigned short*>(smem);           // [64][136] 17408
  unsigned short* hs = reinterpret_cast<unsigned short*>(smem + 17408);   // [64][72]  9216
  float* sOm  = reinterpret_cast<float*>(smem + 26624);                   // [64]
  int*   sTp  = reinterpret_cast<int*>(smem + 26880);                     // [128]
  int*   sBase= reinterpret_cast<int*>(smem + 27392);                     // [16]
  float* stF  = reinterpret_cast<float*>(smem);                           // f32 stage (aliases xs)
  const int tid = threadIdx.x;
  const int t0 = blockIdx.x * 64;

  const int w = tid >> 6, l = tid & 63, lr = l & 15, lg = l >> 4;
  const int gr = tid >> 4, gc = (tid & 15) * 8;
  const f32x4 z4 = {0.f, 0.f, 0.f, 0.f};

  // ---- issue quarter-0 weights FIRST
  const unsigned short* Bw1 = Wu1t;
  const unsigned short* Bw2 = Wu2t;
  bf16x8 W1r[2][4], W2r[2][4];
  LOAD_W1(0, 0); LOAD_W2(0, 0);
  float b1q[4];
#pragma unroll
  for (int hq = 0; hq < 4; ++hq) b1q[hq] = bu1[hq * 64 + w * 16 + lr];
  float b2v[2];
#pragma unroll
  for (int n = 0; n < 2; ++n) b2v[n] = bu2[w * 32 + n * 16 + lr];

  // ---- stage metadata + linear x rows (fully coalesced)
  if (tid < 16) {
    int s = 0;
    for (int i = 0; i < tid; ++i) s += cnt[i * CNT_STRIDE];
    sBase[tid] = s;
  }
  if (tid >= 64 && tid < 128) sOm[tid - 64] = omega[t0 + tid - 64];
  if (tid >= 128) sTp[tid - 128] = tpos[2 * t0 + tid - 128];
#pragma unroll
  for (int p = 0; p < 4; ++p) {
    uint4 v = *reinterpret_cast<const uint4*>(xb + (size_t)(t0 + p * 16 + gr) * kD + gc);
    *reinterpret_cast<uint4*>(&xs[(p * 16 + gr) * LDX + gc]) = v;
  }
  f32x4 acc2[4][2];
#pragma unroll
  for (int m = 0; m < 4; ++m)
#pragma unroll
    for (int n = 0; n < 2; ++n) acc2[m][n] = z4;
  bar_lgkm();                                        // xs + metadata ready

  // ---- four h-quarters (same pipeline; Wu shared by all blocks -> L2 hits)
#pragma unroll
  for (int hq = 0; hq < 4; ++hq) {
    const int cur = hq & 1;
    if (hq < 3) {
      const int nxt = cur ^ 1;
      LOAD_W1(nxt, hq + 1);
      LOAD_W2(nxt, hq + 1);
    }
    f32x4 acc[4];
#pragma unroll
    for (int m = 0; m < 4; ++m) acc[m] = z4;
#pragma unroll
    for (int kk = 0; kk < 4; ++kk) {
      bf16x8 a[4];
#pragma unroll
      for (int m = 0; m < 4; ++m)
        a[m] = *reinterpret_cast<const bf16x8*>(xs + (m * 16 + lr) * LDX + kk * 32 + lg * 8);
#pragma unroll
      for (int m = 0; m < 4; ++m)
        acc[m] = __builtin_amdgcn_mfma_f32_16x16x32_bf16(a[m], W1r[cur][kk], acc[m], 0, 0, 0);
    }
#pragma unroll
    for (int m = 0; m < 4; ++m)
#pragma unroll
      for (int q = 0; q < 4; ++q) {
        float v = acc[m][q] + b1q[hq];
        v = fmaxf(v, 0.f);
        hs[(m * 16 + lg * 4 + q) * LDQ + w * 16 + lr] = f2bf(v);
      }
    bar_lgkm();
#pragma unroll
    for (int k2 = 0; k2 < 2; ++k2) {
      bf16x8 a[4];
#pragma unroll
      for (int m = 0; m < 4; ++m)
        a[m] = *reinterpret_cast<const bf16x8*>(hs + (m * 16 + lr) * LDQ + k2 * 32 + lg * 8);
#pragma unroll
      for (int m = 0; m < 4; ++m)
#pragma unroll
        for (int n = 0; n < 2; ++n)
          acc2[m][n] = __builtin_amdgcn_mfma_f32_16x16x32_bf16(a[m], W2r[cur][n * 2 + k2], acc2[m][n], 0, 0, 0);
    }
    bar_lgkm();
  }

  // ---- epilogue: stage omega*(acc2+bu2) in two 64-col passes, fold eo slots
#pragma unroll
  for (int ch = 0; ch < 2; ++ch) {
    if ((w >> 1) == ch) {
#pragma unroll
      for (int m = 0; m < 4; ++m)
#pragma unroll
        for (int q = 0; q < 4; ++q) {
          int r = m * 16 + lg * 4 + q;
          float om = sOm[r];
#pragma unroll
          for (int n = 0; n < 2; ++n)
            stF[r * 68 + (w & 1) * 32 + n * 16 + lr] = om * (acc2[m][n][q] + b2v[n]);
        }
    }
    bar_lgkm();
#pragma unroll
    for (int j = 0; j < 4; ++j) {
      int gidx = j * 256 + tid;
      int r = gidx >> 4, seg = gidx & 15;   // 16 float4 per 64-col half row
      int a0 = sTp[2 * r], a1 = sTp[2 * r + 1];
      size_t e0r = (size_t)(sBase[a0 >> 16] + (a0 & 0xffff)) * kD + ch * 64 + seg * 4;
      size_t e1r = (size_t)(sBase[a1 >> 16] + (a1 & 0xffff)) * kD + ch * 64 + seg * 4;
      u16x4 v0 = *reinterpret_cast<const u16x4*>(eo + e0r);
      u16x4 v1 = *reinterpret_cast<const u16x4*>(eo + e1r);
      float4 v = *reinterpret_cast<const float4*>(&stF[r * 68 + seg * 4]);
      v.x += bf2f(v0[0]) + bf2f(v1[0]);
      v.y += bf2f(v0[1]) + bf2f(v1[1]);
      v.z += bf2f(v0[2]) + bf2f(v1[2]);
      v.w += bf2f(v0[3]) + bf2f(v1[3]);
      *reinterpret_cast<float4*>(out + (size_t)(t0 + r) * kD + ch * 64 + seg * 4) = v;
    }
    bar_lgkm();
  }
}

// ---------- launch ---------------------------------------------------------
extern "C" void kernel_launch(void* const* d_in, const int* in_sizes, int n_in,
                              void* d_out, int out_size, void* d_ws, size_t ws_size,
                              hipStream_t stream) {
  (void)in_sizes; (void)n_in; (void)out_size; (void)ws_size;
  const float* x   = (const float*)d_in[0];
  const float* Wg  = (const float*)d_in[1];
  const float* bg  = (const float*)d_in[2];
  const float* W1  = (const float*)d_in[3];
  const float* b1  = (const float*)d_in[4];
  const float* W2  = (const float*)d_in[5];
  const float* b2  = (const float*)d_in[6];
  const float* Wu1 = (const float*)d_in[7];
  const float* bu1 = (const float*)d_in[8];
  const float* Wu2 = (const float*)d_in[9];
  const float* bu2 = (const float*)d_in[10];
  float* out = (float*)d_out;

  char* ws = (char*)d_ws;
  constexpr size_t OFF_XB    = 0;          // 8,388,608
  constexpr size_t OFF_W1T   = 8388608;    // 1,048,576
  constexpr size_t OFF_W2T   = 9437184;    // 1,048,576
  constexpr size_t OFF_WU1T  = 10485760;   // 65,536
  constexpr size_t OFF_WU2T  = 10551296;   // 65,536
  constexpr size_t OFF_CNT   = 10616832;   // 4,096
  constexpr size_t OFF_TPOS  = 10620928;   // 262,144
  constexpr size_t OFF_BGATE = 13111296;   // 2,228,224
  constexpr size_t OFF_EO    = 15339520;   // bf16: 65536*128*2 = 16,777,216
  constexpr size_t OFF_OM    = 32116736;   // 131,072
  constexpr size_t OFF_XG    = 33554432;   // bf16: 16*32768*128*2 = 134,217,728

  unsigned short* xb   = (unsigned short*)(ws + OFF_XB);
  unsigned short* W1t  = (unsigned short*)(ws + OFF_W1T);
  unsigned short* W2t  = (unsigned short*)(ws + OFF_W2T);
  unsigned short* Wu1t = (unsigned short*)(ws + OFF_WU1T);
  unsigned short* Wu2t = (unsigned short*)(ws + OFF_WU2T);
  int*   cnt   = (int*)(ws + OFF_CNT);
  int*   tpos  = (int*)(ws + OFF_TPOS);
  float* bgate = (float*)(ws + OFF_BGATE);
  unsigned short* eo = (unsigned short*)(ws + OFF_EO);
  float* omega = (float*)(ws + OFF_OM);
  unsigned short* xg = (unsigned short*)(ws + OFF_XG);

  hipMemsetAsync(cnt, 0, kE * CNT_STRIDE * sizeof(int), stream);
  front_kernel<<<NB_TP + NB_GATE, 256, 0, stream>>>(
      x, Wg, bg, W1, W2, Wu1, Wu2,
      xb, W1t, W2t, Wu1t, Wu2t, cnt, bgate, tpos, omega, xg);
  moe_expert_kernel<<<EXP_GRID, 256, 0, stream>>>(
      xg, W1t, W2t, b1, b2, cnt, bgate, eo);
  uni_combine_kernel<<<kT / 64, 256, 0, stream>>>(
      xb, Wu1t, Wu2t, bu1, bu2, omega, cnt, tpos, eo, out);
}

// Round 21
// 68.762 us; speedup vs baseline: 1.0444x; 1.0444x over previous
//
#include <hip/hip_runtime.h>
#include <hip/hip_bf16.h>

constexpr int kT = 32768;   // tokens = B*N
constexpr int kD = 128;
constexpr int kH = 256;
constexpr int kE = 16;

typedef __bf16 bf16x8 __attribute__((ext_vector_type(8)));
typedef unsigned short u16x8 __attribute__((ext_vector_type(8)));
typedef unsigned short u16x4 __attribute__((ext_vector_type(4)));
typedef float f32x4 __attribute__((ext_vector_type(4)));

#define LDX 136   // xs row stride (ushort) = 128 + 8 pad
#define LDQ 72    // hs quarter row stride (ushort) = 64 + 8 pad

constexpr int NB_TP   = 272;     // transpose tiles (17 W1-like + 17 W2-like, 8 each)
constexpr int NB_GATE = kT / 64; // 512
constexpr int CNT_STRIDE = 32;   // counters padded to 128 B (own cache line)
constexpr int EXP_GRID = 1040;   // max expert tiles: 16 + 65536/64

__device__ __forceinline__ unsigned short f2bf(float f) {
  unsigned int u = __float_as_uint(f);
  u += 0x7FFFu + ((u >> 16) & 1u);   // round-to-nearest-even
  return (unsigned short)(u >> 16);
}
__device__ __forceinline__ float bf2f(unsigned short s) {
  return __uint_as_float((unsigned int)s << 16);
}
// barrier WITHOUT the vmcnt(0) drain __syncthreads carries: LDS ops are
// ordered (lgkmcnt 0), register-destined global loads stay in flight.
__device__ __forceinline__ void bar_lgkm() {
  asm volatile("s_waitcnt lgkmcnt(0)" ::: "memory");
  __builtin_amdgcn_s_barrier();
  asm volatile("" ::: "memory");
}

// ---------- fused front-end: weight transpose | gating (+x cast, tpos) ------
__global__ __launch_bounds__(256) void front_kernel(
    const float* __restrict__ x, const float* __restrict__ Wg,
    const float* __restrict__ bg,
    const float* __restrict__ W1, const float* __restrict__ W2,
    const float* __restrict__ Wu1, const float* __restrict__ Wu2,
    unsigned short* __restrict__ xb, unsigned short* __restrict__ W1t,
    unsigned short* __restrict__ W2t, unsigned short* __restrict__ Wu1t,
    unsigned short* __restrict__ Wu2t,
    int* __restrict__ cnt, int* __restrict__ btok, float* __restrict__ bgate,
    int* __restrict__ tpos, float* __restrict__ omega)
{
  __shared__ __align__(16) char smem[46848];
  const int tid = threadIdx.x;
  const int b = blockIdx.x;

  if (b < NB_TP) {
    // ---- LDS-tiled transpose fp32 [R][C] -> bf16 [C][R], 64x64 tiles
    int bb = b;
    const float* src; unsigned short* dst; int R, C, r0, c0;
    if (bb < 136) {                 // W1-like: [128][256] -> [256][128]
      int m = bb >> 3, t8 = bb & 7;
      R = 128; C = 256;
      src = (m < 16) ? W1 + (size_t)m * 32768 : Wu1;
      dst = (m < 16) ? W1t + (size_t)m * 32768 : Wu1t;
      r0 = (t8 & 1) * 64; c0 = (t8 >> 1) * 64;
    } else {                        // W2-like: [256][128] -> [128][256]
      bb -= 136;
      int m = bb >> 3, t8 = bb & 7;
      R = 256; C = 128;
      src = (m < 16) ? W2 + (size_t)m * 32768 : Wu2;
      dst = (m < 16) ? W2t + (size_t)m * 32768 : Wu2t;
      r0 = (t8 >> 1) * 64; c0 = (t8 & 1) * 64;
    }
    unsigned short (*tl)[72] = reinterpret_cast<unsigned short(*)[72]>(smem);
#pragma unroll
    for (int i = 0; i < 4; ++i) {
      int s = i * 256 + tid;
      int r = s >> 4, c4 = s & 15;
      float4 v = *reinterpret_cast<const float4*>(&src[(size_t)(r0 + r) * C + c0 + c4 * 4]);
      tl[c4 * 4 + 0][r] = f2bf(v.x);
      tl[c4 * 4 + 1][r] = f2bf(v.y);
      tl[c4 * 4 + 2][r] = f2bf(v.z);
      tl[c4 * 4 + 3][r] = f2bf(v.w);
    }
    __syncthreads();
#pragma unroll
    for (int i = 0; i < 2; ++i) {
      int s = i * 256 + tid;
      int c = s >> 3, seg = s & 7;
      uint4 v = *reinterpret_cast<const uint4*>(&tl[c][seg * 8]);
      *reinterpret_cast<uint4*>(&dst[(size_t)(c0 + c) * R + r0 + seg * 8]) = v;
    }
    return;
  }

  // ---- gating: logits (fp64 accum, weight-row hoisted), top-2, scatter -----
  {
    float* sWt = reinterpret_cast<float*>(smem);            // [16][132]
    float* sX  = reinterpret_cast<float*>(smem + 8448);     // [64][132]
    float* sL  = reinterpret_cast<float*>(smem + 42240);    // [64][17]
    int* hcnt  = reinterpret_cast<int*>(smem + 46592);      // [16]
    int* hbase = reinterpret_cast<int*>(smem + 46656);      // [16]
    const int t0 = (b - NB_TP) * 64;

    if (tid < kE) hcnt[tid] = 0;
    for (int i = tid; i < kD * kE; i += 256) {              // Wg[d][e] -> sWt[e][d]
      int d = i >> 4, e = i & 15;
      sWt[e * 132 + d] = Wg[i];
    }
    const float4* xv = reinterpret_cast<const float4*>(x + (size_t)t0 * kD);
    for (int i = tid; i < 64 * kD / 4; i += 256) {
      int r = i >> 5, c4 = i & 31;
      *reinterpret_cast<float4*>(&sX[r * 132 + c4 * 4]) = xv[i];
    }
    __syncthreads();

    const int e = tid & 15, tq = tid >> 4;
    const double bgd = (double)bg[e];
    const float4* wr = reinterpret_cast<const float4*>(&sWt[e * 132]);
    double acc[4] = {0.0, 0.0, 0.0, 0.0};    // one chain per token (4-way ILP)
#pragma unroll
    for (int d4 = 0; d4 < 32; ++d4) {
      float4 wa = wr[d4];                    // load weight row once, reuse x4
#pragma unroll
      for (int p = 0; p < 4; ++p) {
        float4 xa = *reinterpret_cast<const float4*>(&sX[(p * 16 + tq) * 132 + d4 * 4]);
        acc[p] += (double)xa.x * (double)wa.x + (double)xa.y * (double)wa.y
                + (double)xa.z * (double)wa.z + (double)xa.w * (double)wa.w;
      }
    }
#pragma unroll
    for (int p = 0; p < 4; ++p)
      sL[(p * 16 + tq) * 17 + e] = (float)(acc[p] + bgd);
    // fold x fp32->bf16 cast here (sX already staged)
#pragma unroll
    for (int p = 0; p < 4; ++p) {
      int idx = p * 256 + tid;
      int r = idx >> 4, c8 = (idx & 15) * 8;
      const float* sp = &sX[r * 132 + c8];
      u16x8 v;
#pragma unroll
      for (int j = 0; j < 8; ++j) v[j] = f2bf(sp[j]);
      *reinterpret_cast<u16x8*>(&xb[(size_t)(t0 + r) * kD + c8]) = v;
    }
    __syncthreads();

    int e0 = 0, e1 = 0, lp0 = 0, lp1 = 0;
    float g0 = 0.f, g1 = 0.f;
    const int t = t0 + tid;
    if (tid < 64) {
      float v0 = -3.4e38f, v1 = -3.4e38f;
      for (int i = 0; i < kE; ++i) {
        float v = sL[tid * 17 + i];
        if (v > v0) { v1 = v0; e1 = e0; v0 = v; e0 = i; }
        else if (v > v1) { v1 = v; e1 = i; }
      }
      float r = expf(v1 - v0);
      g0 = 1.f / (1.f + r);
      g1 = 1.f - g0;
      omega[t] = 1.f - g0;                   // dense omega (uni pass is linear)
      lp0 = atomicAdd(&hcnt[e0], 1);
      lp1 = atomicAdd(&hcnt[e1], 1);
    }
    __syncthreads();
    if (tid < kE)
      hbase[tid] = atomicAdd(&cnt[tid * CNT_STRIDE], hcnt[tid]);
    __syncthreads();
    if (tid < 64) {
      int p0 = hbase[e0] + lp0;
      btok[e0 * kT + p0] = t; bgate[e0 * kT + p0] = g0;
      int p1 = hbase[e1] + lp1;
      btok[e1 * kT + p1] = t; bgate[e1 * kT + p1] = g1;
      tpos[2 * t]     = (e0 << 16) | p0;      // token -> expert slots (for fold)
      tpos[2 * t + 1] = (e1 << 16) | p1;
    }
  }
}

// ---------- expert tiles: R16 moe pipeline, experts only --------------------
#define LOAD_W1(BUF, HQ)                                                      \
  _Pragma("unroll")                                                           \
  for (int kk = 0; kk < 4; ++kk)                                              \
    W1r[BUF][kk] = *reinterpret_cast<const bf16x8*>(                          \
        Bw1 + (size_t)((HQ) * 64 + w * 16 + lr) * kD + kk * 32 + lg * 8);

#define LOAD_W2(BUF, HQ)                                                      \
  _Pragma("unroll")                                                           \
  for (int n = 0; n < 2; ++n)                                                 \
    _Pragma("unroll")                                                         \
    for (int k2 = 0; k2 < 2; ++k2)                                            \
      W2r[BUF][n * 2 + k2] = *reinterpret_cast<const bf16x8*>(                \
          Bw2 + (size_t)(w * 32 + n * 16 + lr) * kH + (HQ) * 64 + k2 * 32 + lg * 8);

__global__ __launch_bounds__(256) void moe_expert_kernel(
    const unsigned short* __restrict__ xb,
    const unsigned short* __restrict__ W1t,
    const unsigned short* __restrict__ W2t,
    const float* __restrict__ b1, const float* __restrict__ b2,
    const int* __restrict__ cnt, const int* __restrict__ btok,
    const float* __restrict__ bgate,
    unsigned short* __restrict__ eo)
{
  __shared__ alignas(16) char smem[27136];
  unsigned short* xs = reinterpret_cast<unsigned short*>(smem);           // [64][136]
  unsigned short* hs = reinterpret_cast<unsigned short*>(smem + 17408);   // [64][72]
  int*   toks = reinterpret_cast<int*>(smem + 26624);                     // [64]
  float* gts  = reinterpret_cast<float*>(smem + 26880);                   // [64]
  unsigned short* stB = reinterpret_cast<unsigned short*>(smem);          // bf16 stage (aliases xs)
  const int tid = threadIdx.x;
  const int bid = blockIdx.x;

  // ---- block -> (e, tile) map; eobase = sum counts of experts < e
  int c16[16];
#pragma unroll
  for (int i = 0; i < 16; ++i) c16[i] = cnt[i * CNT_STRIDE];
  int e = -1, tile = 0, eobase = 0, accb = 0;
#pragma unroll
  for (int i = 0; i < 16; ++i) {
    int tl = (c16[i] + 63) >> 6;
    if (e < 0) {
      if (bid < accb + tl) { e = i; tile = bid - accb; }
      else { accb += tl; eobase += c16[i]; }
    }
  }
  if (e < 0) return;
  const int rows = min(64, c16[e] - tile * 64);

  const int w = tid >> 6, l = tid & 63, lr = l & 15, lg = l >> 4;
  const int gr = tid >> 4, gc = (tid & 15) * 8;
  const f32x4 z4 = {0.f, 0.f, 0.f, 0.f};

  const unsigned short* Bw1 = W1t + (size_t)e * kH * kD;
  const unsigned short* Bw2 = W2t + (size_t)e * kD * kH;
  const float* bs1 = b1 + (size_t)e * kH;
  const float* bs2 = b2 + (size_t)e * kD;

  // ---- issue quarter-0 weights FIRST: they fly during the gather + barrier
  bf16x8 W1r[2][4], W2r[2][4];
  LOAD_W1(0, 0); LOAD_W2(0, 0);
  float b1q[4];
#pragma unroll
  for (int hq = 0; hq < 4; ++hq) b1q[hq] = bs1[hq * 64 + w * 16 + lr];
  float b2v[2];
#pragma unroll
  for (int n = 0; n < 2; ++n) b2v[n] = bs2[w * 32 + n * 16 + lr];

  // ---- gather 64 token rows + metadata
  {
    int tokR[4]; float gtR[4];
#pragma unroll
    for (int p = 0; p < 4; ++p) {
      int r = p * 16 + gr; bool v = r < rows; int bi2 = e * kT + tile * 64 + r;
      tokR[p] = v ? btok[bi2] : 0;
      gtR[p]  = v ? bgate[bi2] : 0.f;
    }
#pragma unroll
    for (int p = 0; p < 4; ++p) {
      uint4 v = *reinterpret_cast<const uint4*>(xb + (size_t)tokR[p] * kD + gc);
      *reinterpret_cast<uint4*>(&xs[(p * 16 + gr) * LDX + gc]) = v;
    }
    if ((tid & 15) == 0) {
#pragma unroll
      for (int p = 0; p < 4; ++p) {
        toks[p * 16 + gr] = tokR[p];
        gts[p * 16 + gr]  = gtR[p];
      }
    }
  }
  f32x4 acc2[4][2];
#pragma unroll
  for (int m = 0; m < 4; ++m)
#pragma unroll
    for (int n = 0; n < 2; ++n) acc2[m][n] = z4;
  bar_lgkm();                                        // xs ready (weights in flight)

  // ---- four h-quarters, weights for hq+1 prefetched across barriers
#pragma unroll
  for (int hq = 0; hq < 4; ++hq) {
    const int cur = hq & 1;
    if (hq < 3) {
      const int nxt = cur ^ 1;
      LOAD_W1(nxt, hq + 1);                          // in flight over 2 barriers
      LOAD_W2(nxt, hq + 1);
    }
    f32x4 acc[4];
#pragma unroll
    for (int m = 0; m < 4; ++m) acc[m] = z4;
#pragma unroll
    for (int kk = 0; kk < 4; ++kk) {
      bf16x8 a[4];
#pragma unroll
      for (int m = 0; m < 4; ++m)
        a[m] = *reinterpret_cast<const bf16x8*>(xs + (m * 16 + lr) * LDX + kk * 32 + lg * 8);
#pragma unroll
      for (int m = 0; m < 4; ++m)
        acc[m] = __builtin_amdgcn_mfma_f32_16x16x32_bf16(a[m], W1r[cur][kk], acc[m], 0, 0, 0);
    }
#pragma unroll
    for (int m = 0; m < 4; ++m)
#pragma unroll
      for (int q = 0; q < 4; ++q) {
        float v = acc[m][q] + b1q[hq];
        v = fmaxf(v, 0.f);
        hs[(m * 16 + lg * 4 + q) * LDQ + w * 16 + lr] = f2bf(v);
      }
    bar_lgkm();                                      // hs quarter ready
#pragma unroll
    for (int k2 = 0; k2 < 2; ++k2) {
      bf16x8 a[4];
#pragma unroll
      for (int m = 0; m < 4; ++m)
        a[m] = *reinterpret_cast<const bf16x8*>(hs + (m * 16 + lr) * LDQ + k2 * 32 + lg * 8);
#pragma unroll
      for (int m = 0; m < 4; ++m)
#pragma unroll
        for (int n = 0; n < 2; ++n)
          acc2[m][n] = __builtin_amdgcn_mfma_f32_16x16x32_bf16(a[m], W2r[cur][n * 2 + k2], acc2[m][n], 0, 0, 0);
    }
    bar_lgkm();                                      // hs consumed (next quarter)
  }

  // ---- epilogue: stage g*(acc2+b2) bf16, full-line vector stores to eo
#pragma unroll
  for (int m = 0; m < 4; ++m)
#pragma unroll
    for (int q = 0; q < 4; ++q) {
      int r = m * 16 + lg * 4 + q;
      float g = gts[r];
#pragma unroll
      for (int n = 0; n < 2; ++n)
        stB[r * LDX + w * 32 + n * 16 + lr] = f2bf(g * (acc2[m][n][q] + b2v[n]));
    }
  bar_lgkm();
  unsigned short* dst = eo + (size_t)(eobase + tile * 64) * kD;
#pragma unroll
  for (int j = 0; j < 4; ++j) {
    int gidx = j * 256 + tid;
    int r = gidx >> 4, seg = gidx & 15;
    if (r < rows) {
      uint4 v = *reinterpret_cast<const uint4*>(&stB[r * LDX + seg * 8]);
      *reinterpret_cast<uint4*>(dst + (size_t)r * kD + seg * 8) = v;
    }
  }
}

// ---------- uni + combine: linear tiles, out = omega*uni + eo0 + eo1 --------
__global__ __launch_bounds__(256) void uni_combine_kernel(
    const unsigned short* __restrict__ xb,
    const unsigned short* __restrict__ Wu1t,
    const unsigned short* __restrict__ Wu2t,
    const float* __restrict__ bu1, const float* __restrict__ bu2,
    const float* __restrict__ omega, const int* __restrict__ cnt,
    const int* __restrict__ tpos, const unsigned short* __restrict__ eo,
    float* __restrict__ out)
{
  __shared__ alignas(16) char smem[27456];
  unsigned short* xs = reinterpret_cast<unsigned short*>(smem);           // [64][136] 17408
  unsigned short* hs = reinterpret_cast<unsigned short*>(smem + 17408);   // [64][72]  9216
  float* sOm  = reinterpret_cast<float*>(smem + 26624);                   // [64]
  int*   sTp  = reinterpret_cast<int*>(smem + 26880);                     // [128]
  int*   sBase= reinterpret_cast<int*>(smem + 27392);                     // [16]
  float* stF  = reinterpret_cast<float*>(smem);                           // f32 stage [64][68] (aliases xs)
  const int tid = threadIdx.x;
  const int t0 = blockIdx.x * 64;

  const int w = tid >> 6, l = tid & 63, lr = l & 15, lg = l >> 4;
  const int gr = tid >> 4, gc = (tid & 15) * 8;
  const f32x4 z4 = {0.f, 0.f, 0.f, 0.f};

  // ---- issue quarter-0 weights FIRST
  const unsigned short* Bw1 = Wu1t;
  const unsigned short* Bw2 = Wu2t;
  bf16x8 W1r[2][4], W2r[2][4];
  LOAD_W1(0, 0); LOAD_W2(0, 0);
  float b1q[4];
#pragma unroll
  for (int hq = 0; hq < 4; ++hq) b1q[hq] = bu1[hq * 64 + w * 16 + lr];
  float b2v[2];
#pragma unroll
  for (int n = 0; n < 2; ++n) b2v[n] = bu2[w * 32 + n * 16 + lr];

  // ---- stage metadata + linear x rows (fully coalesced)
  if (tid < 16) {
    int s = 0;
    for (int i = 0; i < tid; ++i) s += cnt[i * CNT_STRIDE];
    sBase[tid] = s;
  }
  if (tid >= 64 && tid < 128) sOm[tid - 64] = omega[t0 + tid - 64];
  if (tid >= 128) sTp[tid - 128] = tpos[2 * t0 + tid - 128];
#pragma unroll
  for (int p = 0; p < 4; ++p) {
    uint4 v = *reinterpret_cast<const uint4*>(xb + (size_t)(t0 + p * 16 + gr) * kD + gc);
    *reinterpret_cast<uint4*>(&xs[(p * 16 + gr) * LDX + gc]) = v;
  }
  f32x4 acc2[4][2];
#pragma unroll
  for (int m = 0; m < 4; ++m)
#pragma unroll
    for (int n = 0; n < 2; ++n) acc2[m][n] = z4;
  bar_lgkm();                                        // xs + metadata ready

  // ---- four h-quarters (same pipeline; Wu shared by all blocks -> L2 hits)
#pragma unroll
  for (int hq = 0; hq < 4; ++hq) {
    const int cur = hq & 1;
    if (hq < 3) {
      const int nxt = cur ^ 1;
      LOAD_W1(nxt, hq + 1);
      LOAD_W2(nxt, hq + 1);
    }
    f32x4 acc[4];
#pragma unroll
    for (int m = 0; m < 4; ++m) acc[m] = z4;
#pragma unroll
    for (int kk = 0; kk < 4; ++kk) {
      bf16x8 a[4];
#pragma unroll
      for (int m = 0; m < 4; ++m)
        a[m] = *reinterpret_cast<const bf16x8*>(xs + (m * 16 + lr) * LDX + kk * 32 + lg * 8);
#pragma unroll
      for (int m = 0; m < 4; ++m)
        acc[m] = __builtin_amdgcn_mfma_f32_16x16x32_bf16(a[m], W1r[cur][kk], acc[m], 0, 0, 0);
    }
#pragma unroll
    for (int m = 0; m < 4; ++m)
#pragma unroll
      for (int q = 0; q < 4; ++q) {
        float v = acc[m][q] + b1q[hq];
        v = fmaxf(v, 0.f);
        hs[(m * 16 + lg * 4 + q) * LDQ + w * 16 + lr] = f2bf(v);
      }
    bar_lgkm();
#pragma unroll
    for (int k2 = 0; k2 < 2; ++k2) {
      bf16x8 a[4];
#pragma unroll
      for (int m = 0; m < 4; ++m)
        a[m] = *reinterpret_cast<const bf16x8*>(hs + (m * 16 + lr) * LDQ + k2 * 32 + lg * 8);
#pragma unroll
      for (int m = 0; m < 4; ++m)
#pragma unroll
        for (int n = 0; n < 2; ++n)
          acc2[m][n] = __builtin_amdgcn_mfma_f32_16x16x32_bf16(a[m], W2r[cur][n * 2 + k2], acc2[m][n], 0, 0, 0);
    }
    bar_lgkm();
  }

  // ---- epilogue: stage omega*(acc2+bu2) in two 64-col passes, fold eo slots
#pragma unroll
  for (int ch = 0; ch < 2; ++ch) {
    if ((w >> 1) == ch) {
#pragma unroll
      for (int m = 0; m < 4; ++m)
#pragma unroll
        for (int q = 0; q < 4; ++q) {
          int r = m * 16 + lg * 4 + q;
          float om = sOm[r];
#pragma unroll
          for (int n = 0; n < 2; ++n)
            stF[r * 68 + (w & 1) * 32 + n * 16 + lr] = om * (acc2[m][n][q] + b2v[n]);
        }
    }
    bar_lgkm();
#pragma unroll
    for (int j = 0; j < 4; ++j) {
      int gidx = j * 256 + tid;
      int r = gidx >> 4, seg = gidx & 15;   // 16 float4 per 64-col half row
      int a0 = sTp[2 * r], a1 = sTp[2 * r + 1];
      size_t e0r = (size_t)(sBase[a0 >> 16] + (a0 & 0xffff)) * kD + ch * 64 + seg * 4;
      size_t e1r = (size_t)(sBase[a1 >> 16] + (a1 & 0xffff)) * kD + ch * 64 + seg * 4;
      u16x4 v0 = *reinterpret_cast<const u16x4*>(eo + e0r);
      u16x4 v1 = *reinterpret_cast<const u16x4*>(eo + e1r);
      float4 v = *reinterpret_cast<const float4*>(&stF[r * 68 + seg * 4]);
      v.x += bf2f(v0[0]) + bf2f(v1[0]);
      v.y += bf2f(v0[1]) + bf2f(v1[1]);
      v.z += bf2f(v0[2]) + bf2f(v1[2]);
      v.w += bf2f(v0[3]) + bf2f(v1[3]);
      *reinterpret_cast<float4*>(out + (size_t)(t0 + r) * kD + ch * 64 + seg * 4) = v;
    }
    bar_lgkm();
  }
}

// ---------- launch ---------------------------------------------------------
extern "C" void kernel_launch(void* const* d_in, const int* in_sizes, int n_in,
                              void* d_out, int out_size, void* d_ws, size_t ws_size,
                              hipStream_t stream) {
  (void)in_sizes; (void)n_in; (void)out_size; (void)ws_size;
  const float* x   = (const float*)d_in[0];
  const float* Wg  = (const float*)d_in[1];
  const float* bg  = (const float*)d_in[2];
  const float* W1  = (const float*)d_in[3];
  const float* b1  = (const float*)d_in[4];
  const float* W2  = (const float*)d_in[5];
  const float* b2  = (const float*)d_in[6];
  const float* Wu1 = (const float*)d_in[7];
  const float* bu1 = (const float*)d_in[8];
  const float* Wu2 = (const float*)d_in[9];
  const float* bu2 = (const float*)d_in[10];
  float* out = (float*)d_out;

  char* ws = (char*)d_ws;
  constexpr size_t OFF_XB    = 0;          // 8,388,608
  constexpr size_t OFF_W1T   = 8388608;    // 1,048,576
  constexpr size_t OFF_W2T   = 9437184;    // 1,048,576
  constexpr size_t OFF_WU1T  = 10485760;   // 65,536
  constexpr size_t OFF_WU2T  = 10551296;   // 65,536
  constexpr size_t OFF_CNT   = 10616832;   // 4,096
  constexpr size_t OFF_TPOS  = 10620928;   // 262,144
  constexpr size_t OFF_BTOK  = 10883072;   // 17*32768*4 = 2,228,224
  constexpr size_t OFF_BGATE = 13111296;   // 2,228,224
  constexpr size_t OFF_EO    = 15339520;   // bf16: 65536*128*2 = 16,777,216
  constexpr size_t OFF_OM    = 32116736;   // 131,072 -> end ~32.25 MB

  unsigned short* xb   = (unsigned short*)(ws + OFF_XB);
  unsigned short* W1t  = (unsigned short*)(ws + OFF_W1T);
  unsigned short* W2t  = (unsigned short*)(ws + OFF_W2T);
  unsigned short* Wu1t = (unsigned short*)(ws + OFF_WU1T);
  unsigned short* Wu2t = (unsigned short*)(ws + OFF_WU2T);
  int*   cnt   = (int*)(ws + OFF_CNT);
  int*   tpos  = (int*)(ws + OFF_TPOS);
  int*   btok  = (int*)(ws + OFF_BTOK);
  float* bgate = (float*)(ws + OFF_BGATE);
  unsigned short* eo = (unsigned short*)(ws + OFF_EO);
  float* omega = (float*)(ws + OFF_OM);

  hipMemsetAsync(cnt, 0, kE * CNT_STRIDE * sizeof(int), stream);
  front_kernel<<<NB_TP + NB_GATE, 256, 0, stream>>>(
      x, Wg, bg, W1, W2, Wu1, Wu2,
      xb, W1t, W2t, Wu1t, Wu2t, cnt, btok, bgate, tpos, omega);
  moe_expert_kernel<<<EXP_GRID, 256, 0, stream>>>(
      xb, W1t, W2t, b1, b2, cnt, btok, bgate, eo);
  uni_combine_kernel<<<kT / 64, 256, 0, stream>>>(
      xb, Wu1t, Wu2t, bu1, bu2, omega, cnt, tpos, eo, out);
}